// Round 3
// baseline (29.631 us; speedup 1.0000x reference)
//
#include <hip/hip_runtime.h>
#include <math.h>

#define D 256
#define EPS 1e-8f

// loss of one row: logits = {pos, n1, n2} / 0.5, CE with label 0
__device__ __forceinline__ float row_loss(float pos, float na, float nb) {
    float l0 = pos + pos;   // /T with T=0.5
    float l1 = na + na;
    float l2 = nb + nb;
    float m  = fmaxf(l0, fmaxf(l1, l2));
    float e  = expf(l0 - m) + expf(l1 - m) + expf(l2 - m);
    return logf(e) - (l0 - m);
}

// 16 lanes per chunk, exactly one chunk per group (2048 blocks x 256 thr / 16
// = 32768 groups = n_chunks). Explicit 2-deep load pipeline: prefetch the next
// k-slice's 4 float4 while computing the current slice's FMAs. Target <=64
// VGPR so 8 waves/SIMD (32 waves/CU) are resident.
__global__ __launch_bounds__(256, 8) void ntxent_partial_kernel(
    const float* __restrict__ zis, const float* __restrict__ zjs,
    int n_chunks, float* __restrict__ partial)
{
    const int tid   = blockIdx.x * 256 + threadIdx.x;
    const int lane  = threadIdx.x & 15;          // lane within 16-lane group
    const int group = tid >> 4;

    float local = 0.0f;

    if (group < n_chunks) {
        // reps rows: r0 = zj row0, r1 = zj row1, r2 = zi row0, r3 = zi row1
        const float4* zi = (const float4*)(zis + (size_t)group * (2 * D));
        const float4* zj = (const float4*)(zjs + (size_t)group * (2 * D));

        float s00=0.f,s11=0.f,s22=0.f,s33=0.f;
        float s01=0.f,s02=0.f,s03=0.f,s12=0.f,s13=0.f,s23=0.f;

        // prefetch slice 0 (coalesced: 16 consecutive float4 per row per group)
        float4 n0 = zj[lane];
        float4 n1 = zj[64 + lane];
        float4 n2 = zi[lane];
        float4 n3 = zi[64 + lane];

        #pragma unroll
        for (int i = 0; i < 4; ++i) {
            float4 r0 = n0, r1 = n1, r2 = n2, r3 = n3;
            if (i < 3) {
                const int idx = lane + 16 * (i + 1);
                n0 = zj[idx];
                n1 = zj[64 + idx];
                n2 = zi[idx];
                n3 = zi[64 + idx];
            }
            s00 += r0.x*r0.x + r0.y*r0.y + r0.z*r0.z + r0.w*r0.w;
            s11 += r1.x*r1.x + r1.y*r1.y + r1.z*r1.z + r1.w*r1.w;
            s22 += r2.x*r2.x + r2.y*r2.y + r2.z*r2.z + r2.w*r2.w;
            s33 += r3.x*r3.x + r3.y*r3.y + r3.z*r3.z + r3.w*r3.w;
            s01 += r0.x*r1.x + r0.y*r1.y + r0.z*r1.z + r0.w*r1.w;
            s02 += r0.x*r2.x + r0.y*r2.y + r0.z*r2.z + r0.w*r2.w;
            s03 += r0.x*r3.x + r0.y*r3.y + r0.z*r3.z + r0.w*r3.w;
            s12 += r1.x*r2.x + r1.y*r2.y + r1.z*r2.z + r1.w*r2.w;
            s13 += r1.x*r3.x + r1.y*r3.y + r1.z*r3.z + r1.w*r3.w;
            s23 += r2.x*r3.x + r2.y*r3.y + r2.z*r3.z + r2.w*r3.w;
        }

        // butterfly reduce across the 16-lane group; all lanes end with totals
        #pragma unroll
        for (int m = 1; m < 16; m <<= 1) {
            s00 += __shfl_xor(s00, m);
            s11 += __shfl_xor(s11, m);
            s22 += __shfl_xor(s22, m);
            s33 += __shfl_xor(s33, m);
            s01 += __shfl_xor(s01, m);
            s02 += __shfl_xor(s02, m);
            s03 += __shfl_xor(s03, m);
            s12 += __shfl_xor(s12, m);
            s13 += __shfl_xor(s13, m);
            s23 += __shfl_xor(s23, m);
        }

        // lanes 0..3 of each group each compute one row's loss (NEG_IDX):
        //   row0: pos=v02 negs v01,v03 | row1: pos=v13 negs v01,v12
        //   row2: pos=v02 negs v12,v23 | row3: pos=v13 negs v03,v23
        float rl = 0.0f;
        if (lane < 4) {
            const int r = lane;
            float i0 = 1.0f / fmaxf(sqrtf(s00), EPS);
            float i1 = 1.0f / fmaxf(sqrtf(s11), EPS);
            float i2 = 1.0f / fmaxf(sqrtf(s22), EPS);
            float i3 = 1.0f / fmaxf(sqrtf(s33), EPS);
            float v01 = s01 * i0 * i1;
            float v02 = s02 * i0 * i2;
            float v03 = s03 * i0 * i3;
            float v12 = s12 * i1 * i2;
            float v13 = s13 * i1 * i3;
            float v23 = s23 * i2 * i3;
            float pos = (r & 1) ? v13 : v02;
            float na  = (r < 2) ? v01 : ((r == 2) ? v12 : v03);
            float nb  = (r == 0) ? v03 : ((r == 1) ? v12 : v23);
            rl = row_loss(pos, na, nb);
        }
        // fold the 4 row losses (stays within lanes 0-3 of the group)
        rl += __shfl_xor(rl, 1);
        rl += __shfl_xor(rl, 2);
        if (lane == 0) local = rl;
    }

    // block reduction: wave64 butterfly, then tiny LDS combine
    #pragma unroll
    for (int m = 1; m < 64; m <<= 1) local += __shfl_xor(local, m);
    __shared__ float red[4];
    if ((threadIdx.x & 63) == 0) red[threadIdx.x >> 6] = local;
    __syncthreads();
    if (threadIdx.x == 0) partial[blockIdx.x] = red[0] + red[1] + red[2] + red[3];
}

__global__ __launch_bounds__(256) void ntxent_final_kernel(
    const float* __restrict__ partial, int nb, float* __restrict__ out, float scale)
{
    float v = 0.0f;
    for (int i = threadIdx.x; i < nb; i += 256) v += partial[i];
    #pragma unroll
    for (int m = 1; m < 64; m <<= 1) v += __shfl_xor(v, m);
    __shared__ float red[4];
    if ((threadIdx.x & 63) == 0) red[threadIdx.x >> 6] = v;
    __syncthreads();
    if (threadIdx.x == 0) out[0] = (red[0] + red[1] + red[2] + red[3]) * scale;
}

extern "C" void kernel_launch(void* const* d_in, const int* in_sizes, int n_in,
                              void* d_out, int out_size, void* d_ws, size_t ws_size,
                              hipStream_t stream) {
    const float* zis = (const float*)d_in[0];
    const float* zjs = (const float*)d_in[1];
    float* out       = (float*)d_out;
    float* partial   = (float*)d_ws;

    const int B        = in_sizes[0] / D;   // 65536 rows
    const int n_chunks = B / 2;             // 32768 chunks

    int nb = (n_chunks * 16 + 255) / 256;   // 2048 blocks: one 16-lane group per chunk
    size_t cap = ws_size / sizeof(float);
    if (cap < (size_t)nb) nb = (int)(cap > 0 ? cap : 1);

    ntxent_partial_kernel<<<nb, 256, 0, stream>>>(zis, zjs, n_chunks, partial);
    ntxent_final_kernel<<<1, 256, 0, stream>>>(partial, nb, out, 1.0f / (float)B);
}

// Round 4
// 28.454 us; speedup vs baseline: 1.0413x; 1.0413x over previous
//
#include <hip/hip_runtime.h>
#include <math.h>

#define D 256
#define EPS 1e-8f

__device__ __forceinline__ float dot4(float4 u, float4 v) {
    return u.x*v.x + u.y*v.y + u.z*v.z + u.w*v.w;
}

// loss of one row: logits = {pos, n1, n2} / 0.5, CE with label 0
// fast intrinsics: |err| ~1e-6, threshold is 4.4e-2
__device__ __forceinline__ float row_loss(float pos, float na, float nb) {
    float l0 = pos + pos;   // /T with T=0.5
    float l1 = na + na;
    float l2 = nb + nb;
    float m  = fmaxf(l0, fmaxf(l1, l2));
    float e  = __expf(l0 - m) + __expf(l1 - m) + __expf(l2 - m);
    return __logf(e) - (l0 - m);
}

// 16 lanes per chunk, one chunk per group (2048 blocks x 256 thr / 16 = 32768
// groups = n_chunks). All 16 float4 loads issued upfront into named registers
// (max MLP; no min-waves bound so VGPR can grow to ~80, still 6 waves/SIMD).
__global__ __launch_bounds__(256) void ntxent_partial_kernel(
    const float* __restrict__ zis, const float* __restrict__ zjs,
    int n_chunks, float* __restrict__ partial, float scale)
{
    const int tid   = blockIdx.x * 256 + threadIdx.x;
    const int lane  = threadIdx.x & 15;          // lane within 16-lane group
    const int group = tid >> 4;

    float local = 0.0f;

    if (group < n_chunks) {
        // reps rows: a = zj row0, b = zj row1, c = zi row0, d = zi row1
        const float4* zi = (const float4*)(zis + (size_t)group * (2 * D));
        const float4* zj = (const float4*)(zjs + (size_t)group * (2 * D));

        // issue all 16 loads before any compute (coalesced: 16 lanes x 16 B
        // = 256 B contiguous per row per group)
        float4 a0 = zj[lane     ], a1 = zj[lane + 16], a2 = zj[lane + 32], a3 = zj[lane + 48];
        float4 b0 = zj[lane + 64], b1 = zj[lane + 80], b2 = zj[lane + 96], b3 = zj[lane +112];
        float4 c0 = zi[lane     ], c1 = zi[lane + 16], c2 = zi[lane + 32], c3 = zi[lane + 48];
        float4 d0 = zi[lane + 64], d1 = zi[lane + 80], d2 = zi[lane + 96], d3 = zi[lane +112];

        float s00 = dot4(a0,a0) + dot4(a1,a1) + dot4(a2,a2) + dot4(a3,a3);
        float s01 = dot4(a0,b0) + dot4(a1,b1) + dot4(a2,b2) + dot4(a3,b3);
        float s02 = dot4(a0,c0) + dot4(a1,c1) + dot4(a2,c2) + dot4(a3,c3);
        float s03 = dot4(a0,d0) + dot4(a1,d1) + dot4(a2,d2) + dot4(a3,d3);
        float s11 = dot4(b0,b0) + dot4(b1,b1) + dot4(b2,b2) + dot4(b3,b3);
        float s12 = dot4(b0,c0) + dot4(b1,c1) + dot4(b2,c2) + dot4(b3,c3);
        float s13 = dot4(b0,d0) + dot4(b1,d1) + dot4(b2,d2) + dot4(b3,d3);
        float s22 = dot4(c0,c0) + dot4(c1,c1) + dot4(c2,c2) + dot4(c3,c3);
        float s23 = dot4(c0,d0) + dot4(c1,d1) + dot4(c2,d2) + dot4(c3,d3);
        float s33 = dot4(d0,d0) + dot4(d1,d1) + dot4(d2,d2) + dot4(d3,d3);

        // butterfly reduce across the 16-lane group; all lanes end with totals
        #pragma unroll
        for (int m = 1; m < 16; m <<= 1) {
            s00 += __shfl_xor(s00, m);
            s11 += __shfl_xor(s11, m);
            s22 += __shfl_xor(s22, m);
            s33 += __shfl_xor(s33, m);
            s01 += __shfl_xor(s01, m);
            s02 += __shfl_xor(s02, m);
            s03 += __shfl_xor(s03, m);
            s12 += __shfl_xor(s12, m);
            s13 += __shfl_xor(s13, m);
            s23 += __shfl_xor(s23, m);
        }

        // lanes 0..3 of each group each compute one row's loss (NEG_IDX):
        //   row0: pos=v02 negs v01,v03 | row1: pos=v13 negs v01,v12
        //   row2: pos=v02 negs v12,v23 | row3: pos=v13 negs v03,v23
        float rl = 0.0f;
        if (lane < 4) {
            const int r = lane;
            float i0 = __frsqrt_rn(fmaxf(s00, EPS*EPS));
            float i1 = __frsqrt_rn(fmaxf(s11, EPS*EPS));
            float i2 = __frsqrt_rn(fmaxf(s22, EPS*EPS));
            float i3 = __frsqrt_rn(fmaxf(s33, EPS*EPS));
            float v01 = s01 * i0 * i1;
            float v02 = s02 * i0 * i2;
            float v03 = s03 * i0 * i3;
            float v12 = s12 * i1 * i2;
            float v13 = s13 * i1 * i3;
            float v23 = s23 * i2 * i3;
            float pos = (r & 1) ? v13 : v02;
            float na  = (r < 2) ? v01 : ((r == 2) ? v12 : v03);
            float nb  = (r == 0) ? v03 : ((r == 1) ? v12 : v23);
            rl = row_loss(pos, na, nb);
        }
        // fold the 4 row losses (stays within lanes 0-3 of the group)
        rl += __shfl_xor(rl, 1);
        rl += __shfl_xor(rl, 2);
        if (lane == 0) local = rl;
    }

    // block reduction: wave64 butterfly, then tiny LDS combine
    #pragma unroll
    for (int m = 1; m < 64; m <<= 1) local += __shfl_xor(local, m);
    __shared__ float red[4];
    if ((threadIdx.x & 63) == 0) red[threadIdx.x >> 6] = local;
    __syncthreads();
    if (threadIdx.x == 0)
        partial[blockIdx.x] = (red[0] + red[1] + red[2] + red[3]) * scale;
}

__global__ __launch_bounds__(256) void ntxent_final_kernel(
    const float* __restrict__ partial, int nb, float* __restrict__ out)
{
    float v = 0.0f;
    for (int i = threadIdx.x; i < nb; i += 256) v += partial[i];
    #pragma unroll
    for (int m = 1; m < 64; m <<= 1) v += __shfl_xor(v, m);
    __shared__ float red[4];
    if ((threadIdx.x & 63) == 0) red[threadIdx.x >> 6] = v;
    __syncthreads();
    if (threadIdx.x == 0) out[0] = red[0] + red[1] + red[2] + red[3];
}

extern "C" void kernel_launch(void* const* d_in, const int* in_sizes, int n_in,
                              void* d_out, int out_size, void* d_ws, size_t ws_size,
                              hipStream_t stream) {
    const float* zis = (const float*)d_in[0];
    const float* zjs = (const float*)d_in[1];
    float* out       = (float*)d_out;
    float* partial   = (float*)d_ws;

    const int B        = in_sizes[0] / D;   // 65536 rows
    const int n_chunks = B / 2;             // 32768 chunks

    int nb = (n_chunks * 16 + 255) / 256;   // 2048 blocks: one 16-lane group per chunk
    size_t cap = ws_size / sizeof(float);
    if (cap < (size_t)nb) nb = (int)(cap > 0 ? cap : 1);

    ntxent_partial_kernel<<<nb, 256, 0, stream>>>(zis, zjs, n_chunks, partial,
                                                  1.0f / (float)B);
    ntxent_final_kernel<<<1, 256, 0, stream>>>(partial, nb, out);
}